// Round 14
// baseline (217.160 us; speedup 1.0000x reference)
//
#include <hip/hip_runtime.h>
#include <cstdint>
#include <cstddef>

#define SEQ   2048
#define BBAT  2
#define EMBED 512
#define NH    8
#define HD    64
#define NPOS  34

typedef __bf16 bf16;
typedef __bf16 bf16x8 __attribute__((ext_vector_type(8)));
typedef float  f32x4  __attribute__((ext_vector_type(4)));
typedef int    int32x4 __attribute__((ext_vector_type(4)));

// scale = log2(e)/8 : energy=(qk+bias)/8, computed in exp2 domain.
// ESCALE is folded into Qp at the projection epilogue (z==0).
#define ESCALE 0.1803368801111204f

__device__ __forceinline__ f32x4 mfma16(bf16x8 a, bf16x8 b, f32x4 c){
  return __builtin_amdgcn_mfma_f32_16x16x32_bf16(a, b, c, 0, 0, 0);
}

// lgkm-only barrier: does NOT drain vmcnt, so prefetch global loads stay in
// flight across it. sched_barrier(0) pins LDS ops on the correct side.
__device__ __forceinline__ void barrier_lgkm(){
  asm volatile("s_waitcnt lgkmcnt(0)" ::: "memory");
  __builtin_amdgcn_s_barrier();
  __builtin_amdgcn_sched_barrier(0);
}

// ---------------- kernel 1: fused prep (verbatim R4/R7) ----------------
__global__ __launch_bounds__(256) void k_prep(
    const float* __restrict__ Q, const float* __restrict__ K, const float* __restrict__ V,
    const float* __restrict__ Wq, const float* __restrict__ Wk,
    const float* __restrict__ Wv, const float* __restrict__ Wo,
    const float* __restrict__ RE,
    bf16* __restrict__ Qb, bf16* __restrict__ Kb, bf16* __restrict__ Vb,
    bf16* __restrict__ Wall, bf16* __restrict__ Rb)
{
  const int NCONV = 3*524288;
  const int NW = 196608, NO = 262144;
  int i = blockIdx.x*256 + threadIdx.x;
  if (i < NCONV){
    int tsel = i >> 19, j = i & 524287;
    const float* s = tsel==0 ? Q : (tsel==1 ? K : V);
    bf16* d       = tsel==0 ? Qb : (tsel==1 ? Kb : Vb);
    float4 v = ((const float4*)s)[j];
    union { bf16 e[4]; ushort4 u; } pk;
    pk.e[0]=(bf16)v.x; pk.e[1]=(bf16)v.y; pk.e[2]=(bf16)v.z; pk.e[3]=(bf16)v.w;
    ((ushort4*)d)[j] = pk.u;
  } else {
    int j = i - NCONV;
    if (j < NW){
      int w  = j >> 16;
      int r  = j & 65535;
      int np = r >> 7, c4 = (r & 127) << 2;
      const float* W = (w==0) ? Wq : ((w==1) ? Wk : Wv);
      int src = ((np & 63) << 3) + (np >> 6);
      float4 v = *(const float4*)(W + (size_t)src*512 + c4);
      union { bf16 e[4]; ushort4 u; } pk;
      pk.e[0]=(bf16)v.x; pk.e[1]=(bf16)v.y; pk.e[2]=(bf16)v.z; pk.e[3]=(bf16)v.w;
      *(ushort4*)(Wall + (size_t)w*262144 + (size_t)np*512 + c4) = pk.u;
    } else if (j < NW + NO){
      int jj = j - NW;
      int n = jj >> 9, kp = jj & 511;
      int src = ((kp & 63) << 3) + (kp >> 6);
      Wall[(size_t)3*262144 + (size_t)n*512 + kp] = (bf16)Wo[(size_t)n*512 + src];
    } else {
      int jj = j - NW - NO;
      if (jj < 8*48*64){
        int h  = jj / (48*64);
        int r2 = jj - h*(48*64);
        int p  = r2 >> 6, dd = r2 & 63;
        float v = (p < NPOS) ? RE[(size_t)p*512 + dd*8 + h] : 0.f;
        Rb[jj] = (bf16)v;
      }
    }
  }
}

// ---------------- kernel 2: projections, 128x128 tile, reg-dbuf pipelined (verbatim R7) ----------------
__global__ __launch_bounds__(256,2) void k_proj(
    const bf16* __restrict__ Qb, const bf16* __restrict__ Kb, const bf16* __restrict__ Vb,
    const bf16* __restrict__ W,
    bf16* __restrict__ Qp, bf16* __restrict__ Kp, bf16* __restrict__ Vt)
{
  const int z = blockIdx.z;
  const bf16* A  = z==0 ? Qb : (z==1 ? Kb : Vb);
  const bf16* Bw = W + (size_t)z*262144;

  __shared__ __align__(16) bf16 AB[2][128][72];
  bf16 (*As)[72] = AB[0];
  bf16 (*Bs)[72] = AB[1];

  const int t = threadIdx.x;
  const int w = t >> 6, lane = t & 63, l15 = lane & 15, quad = lane >> 4;
  const int wm = (w & 1) * 64, wn = (w >> 1) * 64;
  const int m0 = blockIdx.y * 128, n0 = blockIdx.x * 128;
  const int row = t >> 3, c8 = (t & 7) << 3;

  const bf16* Abase = A  + (size_t)(m0 + row)*512 + c8;
  const bf16* Bbase = Bw + (size_t)(n0 + row)*512 + c8;

  uint4 pa0,pa1,pa2,pa3, pb0,pb1,pb2,pb3;
  uint4 qa0,qa1,qa2,qa3, qb0,qb1,qb2,qb3;
  pa0 = *(const uint4*)(Abase);
  pa1 = *(const uint4*)(Abase + 32*512);
  pa2 = *(const uint4*)(Abase + 64*512);
  pa3 = *(const uint4*)(Abase + 96*512);
  pb0 = *(const uint4*)(Bbase);
  pb1 = *(const uint4*)(Bbase + 32*512);
  pb2 = *(const uint4*)(Bbase + 64*512);
  pb3 = *(const uint4*)(Bbase + 96*512);

  f32x4 acc[4][4];
  #pragma unroll
  for (int mt=0; mt<4; ++mt)
    #pragma unroll
    for (int nt=0; nt<4; ++nt) acc[mt][nt] = (f32x4){0.f,0.f,0.f,0.f};

#define PROJ_BODY(KT, A0,A1,A2,A3, B0,B1,B2,B3, LA0,LA1,LA2,LA3, LB0,LB1,LB2,LB3) \
  {                                                                             \
    barrier_lgkm();                                                             \
    *(uint4*)&As[row     ][c8] = A0;                                            \
    *(uint4*)&As[row + 32][c8] = A1;                                            \
    *(uint4*)&As[row + 64][c8] = A2;                                            \
    *(uint4*)&As[row + 96][c8] = A3;                                            \
    *(uint4*)&Bs[row     ][c8] = B0;                                            \
    *(uint4*)&Bs[row + 32][c8] = B1;                                            \
    *(uint4*)&Bs[row + 64][c8] = B2;                                            \
    *(uint4*)&Bs[row + 96][c8] = B3;                                            \
    if ((KT) < 7){                                                              \
      const bf16* ap2 = Abase + ((KT)+1)*64;                                    \
      const bf16* bp2 = Bbase + ((KT)+1)*64;                                    \
      LA0 = *(const uint4*)(ap2);                                               \
      LA1 = *(const uint4*)(ap2 + 32*512);                                      \
      LA2 = *(const uint4*)(ap2 + 64*512);                                      \
      LA3 = *(const uint4*)(ap2 + 96*512);                                      \
      LB0 = *(const uint4*)(bp2);                                               \
      LB1 = *(const uint4*)(bp2 + 32*512);                                      \
      LB2 = *(const uint4*)(bp2 + 64*512);                                      \
      LB3 = *(const uint4*)(bp2 + 96*512);                                      \
    }                                                                           \
    barrier_lgkm();                                                             \
    __builtin_amdgcn_s_setprio(1);                                              \
    _Pragma("unroll")                                                           \
    for (int ks = 0; ks < 2; ++ks){                                             \
      bf16x8 am[4], bn[4];                                                      \
      _Pragma("unroll")                                                         \
      for (int x=0;x<4;++x) am[x] = *(const bf16x8*)&As[wm + x*16 + l15][ks*32 + quad*8]; \
      _Pragma("unroll")                                                         \
      for (int y=0;y<4;++y) bn[y] = *(const bf16x8*)&Bs[wn + y*16 + l15][ks*32 + quad*8]; \
      _Pragma("unroll")                                                         \
      for (int mt=0;mt<4;++mt)                                                  \
        _Pragma("unroll")                                                       \
        for (int nt=0;nt<4;++nt)                                                \
          acc[mt][nt] = mfma16(am[mt], bn[nt], acc[mt][nt]);                    \
    }                                                                           \
    __builtin_amdgcn_s_setprio(0);                                              \
  }

  for (int kt2 = 0; kt2 < 8; kt2 += 2){
    PROJ_BODY(kt2,     pa0,pa1,pa2,pa3, pb0,pb1,pb2,pb3, qa0,qa1,qa2,qa3, qb0,qb1,qb2,qb3)
    PROJ_BODY(kt2 + 1, qa0,qa1,qa2,qa3, qb0,qb1,qb2,qb3, pa0,pa1,pa2,pa3, pb0,pb1,pb2,pb3)
  }
#undef PROJ_BODY

  if (z != 2){
    bf16* C = z==0 ? Qp : Kp;
    const float scl = (z==0) ? ESCALE : 1.0f;
    #pragma unroll
    for (int mt=0;mt<4;++mt)
      #pragma unroll
      for (int r=0;r<4;++r){
        int m = m0 + wm + mt*16 + quad*4 + r;
        #pragma unroll
        for (int nt=0;nt<4;++nt)
          C[(size_t)m*512 + n0 + wn + nt*16 + l15] = (bf16)(acc[mt][nt][r] * scl);
      }
  } else {
    __syncthreads();
    bf16 (*VT)[136] = (bf16(*)[136])AB;
    #pragma unroll
    for (int mt=0;mt<4;++mt)
      #pragma unroll
      for (int r=0;r<4;++r){
        int m = wm + mt*16 + quad*4 + r;
        #pragma unroll
        for (int nt=0;nt<4;++nt)
          VT[wn + nt*16 + l15][m] = (bf16)acc[mt][nt][r];
      }
    __syncthreads();
    const int b = m0 >> 11, s0 = m0 & 2047;
    const int n = t >> 1, c0 = (t & 1) * 64;
    const int h = blockIdx.x*2 + (n >> 6), d = n & 63;
    bf16* dst = Vt + ((size_t)((b*NH + h)*HD + d))*SEQ + s0 + c0;
    #pragma unroll
    for (int i = 0; i < 8; ++i)
      *(uint4*)(dst + i*8) = *(const uint4*)&VT[n][c0 + i*8];
  }
}

// ---------------- kernel 4: output projection, 128x128 tile, same pipeline (verbatim R7) ----------------
__global__ __launch_bounds__(256,2) void k_gemm_out(
    const bf16* __restrict__ A, const bf16* __restrict__ Bw, float* __restrict__ C)
{
  __shared__ __align__(16) bf16 AB[2][128][72];
  bf16 (*As)[72] = AB[0];
  bf16 (*Bs)[72] = AB[1];

  const int t = threadIdx.x;
  const int w = t >> 6, lane = t & 63, l15 = lane & 15, quad = lane >> 4;
  const int wm = (w & 1) * 64, wn = (w >> 1) * 64;
  const int m0 = blockIdx.y * 128, n0 = blockIdx.x * 128;
  const int row = t >> 3, c8 = (t & 7) << 3;

  const bf16* Abase = A  + (size_t)(m0 + row)*512 + c8;
  const bf16* Bbase = Bw + (size_t)(n0 + row)*512 + c8;

  uint4 pa0,pa1,pa2,pa3, pb0,pb1,pb2,pb3;
  uint4 qa0,qa1,qa2,qa3, qb0,qb1,qb2,qb3;
  pa0 = *(const uint4*)(Abase);
  pa1 = *(const uint4*)(Abase + 32*512);
  pa2 = *(const uint4*)(Abase + 64*512);
  pa3 = *(const uint4*)(Abase + 96*512);
  pb0 = *(const uint4*)(Bbase);
  pb1 = *(const uint4*)(Bbase + 32*512);
  pb2 = *(const uint4*)(Bbase + 64*512);
  pb3 = *(const uint4*)(Bbase + 96*512);

  f32x4 acc[4][4];
  #pragma unroll
  for (int mt=0; mt<4; ++mt)
    #pragma unroll
    for (int nt=0; nt<4; ++nt) acc[mt][nt] = (f32x4){0.f,0.f,0.f,0.f};

#define OUT_BODY(KT, A0,A1,A2,A3, B0,B1,B2,B3, LA0,LA1,LA2,LA3, LB0,LB1,LB2,LB3) \
  {                                                                             \
    barrier_lgkm();                                                             \
    *(uint4*)&As[row     ][c8] = A0;                                            \
    *(uint4*)&As[row + 32][c8] = A1;                                            \
    *(uint4*)&As[row + 64][c8] = A2;                                            \
    *(uint4*)&As[row + 96][c8] = A3;                                            \
    *(uint4*)&Bs[row     ][c8] = B0;                                            \
    *(uint4*)&Bs[row + 32][c8] = B1;                                            \
    *(uint4*)&Bs[row + 64][c8] = B2;                                            \
    *(uint4*)&Bs[row + 96][c8] = B3;                                            \
    if ((KT) < 7){                                                              \
      const bf16* ap2 = Abase + ((KT)+1)*64;                                    \
      const bf16* bp2 = Bbase + ((KT)+1)*64;                                    \
      LA0 = *(const uint4*)(ap2);                                               \
      LA1 = *(const uint4*)(ap2 + 32*512);                                      \
      LA2 = *(const uint4*)(ap2 + 64*512);                                      \
      LA3 = *(const uint4*)(ap2 + 96*512);                                      \
      LB0 = *(const uint4*)(bp2);                                               \
      LB1 = *(const uint4*)(bp2 + 32*512);                                      \
      LB2 = *(const uint4*)(bp2 + 64*512);                                      \
      LB3 = *(const uint4*)(bp2 + 96*512);                                      \
    }                                                                           \
    barrier_lgkm();                                                             \
    __builtin_amdgcn_s_setprio(1);                                              \
    _Pragma("unroll")                                                           \
    for (int ks = 0; ks < 2; ++ks){                                             \
      bf16x8 am[4], bn[4];                                                      \
      _Pragma("unroll")                                                         \
      for (int x=0;x<4;++x) am[x] = *(const bf16x8*)&As[wm + x*16 + l15][ks*32 + quad*8]; \
      _Pragma("unroll")                                                         \
      for (int y=0;y<4;++y) bn[y] = *(const bf16x8*)&Bs[wn + y*16 + l15][ks*32 + quad*8]; \
      _Pragma("unroll")                                                         \
      for (int mt=0;mt<4;++mt)                                                  \
        _Pragma("unroll")                                                       \
        for (int nt=0;nt<4;++nt)                                                \
          acc[mt][nt] = mfma16(am[mt], bn[nt], acc[mt][nt]);                    \
    }                                                                           \
    __builtin_amdgcn_s_setprio(0);                                              \
  }

  for (int kt2 = 0; kt2 < 8; kt2 += 2){
    OUT_BODY(kt2,     pa0,pa1,pa2,pa3, pb0,pb1,pb2,pb3, qa0,qa1,qa2,qa3, qb0,qb1,qb2,qb3)
    OUT_BODY(kt2 + 1, qa0,qa1,qa2,qa3, qb0,qb1,qb2,qb3, pa0,pa1,pa2,pa3, pb0,pb1,pb2,pb3)
  }
#undef OUT_BODY

  #pragma unroll
  for (int mt=0;mt<4;++mt)
    #pragma unroll
    for (int r=0;r<4;++r){
      int m = m0 + wm + mt*16 + quad*4 + r;
      #pragma unroll
      for (int nt=0;nt<4;++nt)
        C[(size_t)m*512 + n0 + wn + nt*16 + l15] = acc[mt][nt][r];
    }
}

// ---------------- kernel 3: flash attention v9 -- 8 waves / 512 threads ----------------
// R12 evidence: OccupancyPercent 17 (grid 512 x 256thr = 2 WG/CU = 25% cap),
// no pipe saturated -> latency-bound, G1 lever never pulled. v9: 512-thread
// blocks (8 waves), same grid -> 16 waves/CU (50%). Wave (qh, ks):
//   QK: 32q x 32k (k split 4-way); softmax+Ps write for own chunk.
//   PV: d-split -- wave owns d-chunk ks*16 over FULL k=128 -> O fully summed
//       per wave => epilogue cross-wave O-exchange DELETED (only 4-way lsum).
// Ps is now cross-wave -> 3rd lgkm barrier per tile (paid for by 2x TLP).
// Staging identical traffic, split across 2x threads. acc 32->8 VGPRs.
__global__ __launch_bounds__(512,4) void k_attn(
    const bf16* __restrict__ Qp, const bf16* __restrict__ Kp,
    const bf16* __restrict__ Vt, const bf16* __restrict__ Rb,
    const int* __restrict__ ids, bf16* __restrict__ Out)
{
  // LDS: 18432 + 17408 + 17408 + 9100 + 1024 = 63372 B -> 2 WG/CU (16 waves)
  __shared__ __align__(16) bf16 Ks[128][72];
  __shared__ __align__(16) bf16 Vs[64][136];
  __shared__ __align__(16) bf16 Ps[64][136];
  __shared__ float lutT[35][65];
  __shared__ float lsum_s[4][64];

  const int t = threadIdx.x;                    // 0..511
  const int b = blockIdx.z, h = blockIdx.y;
  const int q0 = blockIdx.x * 64;
  const int w = t >> 6;                         // 0..7
  const int lane = t & 63, l15 = lane & 15, quad = lane >> 4;
  const int qh = w & 1, ks = w >> 1;            // ks: QK k-chunk AND PV d-chunk

  const size_t idb = (size_t)b*SEQ*SEQ;
  const bf16* kbase = Kp + (size_t)b*SEQ*EMBED + h*HD;
  const bf16* vbase = Vt + (size_t)(b*NH + h)*HD*SEQ;

  // staging geometry (512 threads): K rows krow/krow+64 ; V rows vrow/vrow+32
  const int krow = t >> 3, kcol = (t & 7) << 3;
  const int vrow = t >> 4, vcol = (t & 15) << 3;

  uint4 ka0, ka1, va0, va1;
  uint4 kb0, kb1, vb0, vb1;
  ka0 = *(const uint4*)(kbase + (size_t)(krow     )*EMBED + kcol);
  ka1 = *(const uint4*)(kbase + (size_t)(krow + 64)*EMBED + kcol);
  va0 = *(const uint4*)(vbase + (size_t)(vrow     )*SEQ + vcol);
  va1 = *(const uint4*)(vbase + (size_t)(vrow + 32)*SEQ + vcol);

  // ---- prefetch tile-0 ids: q = qh*32+mt*16+l15, k = ks*32+nt*16+quad*4 ----
  int32x4 nid[2][2];
  #pragma unroll
  for (int mt=0; mt<2; ++mt)
    #pragma unroll
    for (int nt=0; nt<2; ++nt)
      nid[mt][nt] = *(const int32x4*)(ids + idb
          + (size_t)(q0 + qh*32 + mt*16 + l15)*SEQ
          + ks*32 + nt*16 + quad*4);

  // ---- build LUT via MFMA (waves 0-3 only; rows are in-tile there) ----
  if (w < 4){
    const bf16* qbrow = Qp + (size_t)(b*SEQ + q0 + w*16 + l15)*EMBED + h*HD;
    bf16x8 ab0 = *(const bf16x8*)(qbrow + quad*8);
    bf16x8 ab1 = *(const bf16x8*)(qbrow + 32 + quad*8);
    const bf16* rh = Rb + h*3072;
    #pragma unroll
    for (int nt = 0; nt < 3; ++nt){
      bf16x8 r0 = *(const bf16x8*)(rh + (nt*16 + l15)*64 + quad*8);
      bf16x8 r1 = *(const bf16x8*)(rh + (nt*16 + l15)*64 + 32 + quad*8);
      f32x4 c = (f32x4){0.f,0.f,0.f,0.f};
      c = mfma16(ab0, r0, c);
      c = mfma16(ab1, r1, c);
      int p = nt*16 + l15;
      if (p < NPOS){
        #pragma unroll
        for (int r = 0; r < 4; ++r)
          lutT[p][w*16 + quad*4 + r] = (p == 0) ? -1e30f : c[r];
      }
    }
  }

  // ---- QK B-frags (Q rows, reg-resident) ----
  bf16x8 bq[2][2];
  #pragma unroll
  for (int mt = 0; mt < 2; ++mt){
    const bf16* qrow = Qp + (size_t)(b*SEQ + q0 + qh*32 + mt*16 + l15)*EMBED + h*HD;
    bq[mt][0] = *(const bf16x8*)(qrow + quad*8);
    bq[mt][1] = *(const bf16x8*)(qrow + 32 + quad*8);
  }

  __syncthreads();   // lutT visible to all 8 waves

  f32x4 acc[2];
  acc[0] = (f32x4){0.f,0.f,0.f,0.f};
  acc[1] = (f32x4){0.f,0.f,0.f,0.f};
  float lsum[2] = {0.f, 0.f};

#define ATTN_BODY(KT, K0,K1, V0,V1, L0,L1, M0,M1)                              \
  {                                                                            \
    barrier_lgkm();  /* B1: all waves done with Ks/Vs/Ps of prev tile */       \
    *(uint4*)&Ks[krow     ][kcol] = K0;                                        \
    *(uint4*)&Ks[krow + 64][kcol] = K1;                                        \
    *(uint4*)&Vs[vrow     ][vcol] = V0;                                        \
    *(uint4*)&Vs[vrow + 32][vcol] = V1;                                        \
    if ((KT) < 15){                                                            \
      const bf16* kp2 = kbase + (size_t)(((KT)+1)*128)*EMBED + kcol;           \
      const bf16* vp2 = vbase + ((KT)+1)*128 + vcol;                           \
      L0 = *(const uint4*)(kp2 + (size_t)(krow     )*EMBED);                   \
      L1 = *(const uint4*)(kp2 + (size_t)(krow + 64)*EMBED);                   \
      M0 = *(const uint4*)(vp2 + (size_t)(vrow     )*SEQ);                     \
      M1 = *(const uint4*)(vp2 + (size_t)(vrow + 32)*SEQ);                     \
    }                                                                          \
    barrier_lgkm();  /* B2: staged tile ready; prefetch loads keep flying */   \
    float wvv[2][2][4];                                                        \
    _Pragma("unroll")                                                          \
    for (int mt = 0; mt < 2; ++mt){                                            \
      const float* lcol = &lutT[0][qh*32 + mt*16 + l15];                       \
      _Pragma("unroll")                                                        \
      for (int nt = 0; nt < 2; ++nt){                                          \
        int32x4 v = nid[mt][nt];                                               \
        wvv[mt][nt][0] = lcol[v[0] * 65];                                      \
        wvv[mt][nt][1] = lcol[v[1] * 65];                                      \
        wvv[mt][nt][2] = lcol[v[2] * 65];                                      \
        wvv[mt][nt][3] = lcol[v[3] * 65];                                      \
      }                                                                        \
    }                                                                          \
    if ((KT) < 15){                                                            \
      _Pragma("unroll")                                                        \
      for (int mt = 0; mt < 2; ++mt)                                           \
        _Pragma("unroll")                                                      \
        for (int nt = 0; nt < 2; ++nt)                                         \
          nid[mt][nt] = *(const int32x4*)(ids + idb                            \
              + (size_t)(q0 + qh*32 + mt*16 + l15)*SEQ                         \
              + (((KT)+1)*128) + ks*32 + nt*16 + quad*4);                      \
    }                                                                          \
    f32x4 sf[2][2];                                                            \
    __builtin_amdgcn_s_setprio(1);                                             \
    _Pragma("unroll")                                                          \
    for (int nt = 0; nt < 2; ++nt){                                            \
      bf16x8 ak0 = *(const bf16x8*)&Ks[ks*32 + nt*16 + l15][quad*8];           \
      bf16x8 ak1 = *(const bf16x8*)&Ks[ks*32 + nt*16 + l15][32 + quad*8];      \
      _Pragma("unroll")                                                        \
      for (int mt = 0; mt < 2; ++mt){                                          \
        f32x4 c = (f32x4){0.f,0.f,0.f,0.f};                                    \
        c = mfma16(ak0, bq[mt][0], c);                                         \
        c = mfma16(ak1, bq[mt][1], c);                                         \
        sf[mt][nt] = c;                                                        \
      }                                                                        \
    }                                                                          \
    __builtin_amdgcn_s_setprio(0);                                             \
    _Pragma("unroll")                                                          \
    for (int mt = 0; mt < 2; ++mt){                                            \
      _Pragma("unroll")                                                        \
      for (int nt = 0; nt < 2; ++nt){                                          \
        union { bf16 e[4]; uint2 u; } pk;                                      \
        float p0 = __builtin_amdgcn_exp2f(sf[mt][nt][0] + wvv[mt][nt][0]);     \
        float p1 = __builtin_amdgcn_exp2f(sf[mt][nt][1] + wvv[mt][nt][1]);     \
        float p2 = __builtin_amdgcn_exp2f(sf[mt][nt][2] + wvv[mt][nt][2]);     \
        float p3 = __builtin_amdgcn_exp2f(sf[mt][nt][3] + wvv[mt][nt][3]);     \
        pk.e[0] = (bf16)p0; pk.e[1] = (bf16)p1;                                \
        pk.e[2] = (bf16)p2; pk.e[3] = (bf16)p3;                                \
        lsum[mt] += (p0 + p1) + (p2 + p3);                                     \
        *(uint2*)&Ps[qh*32 + mt*16 + l15][ks*32 + nt*16 + quad*4] = pk.u;      \
      }                                                                        \
    }                                                                          \
    barrier_lgkm();  /* B3: Ps complete (cross-wave) */                        \
    __builtin_amdgcn_s_setprio(1);                                             \
    _Pragma("unroll")                                                          \
    for (int kk = 0; kk < 4; ++kk){                                            \
      bf16x8 ap0 = *(const bf16x8*)&Ps[qh*32      + l15][kk*32 + quad*8];      \
      bf16x8 ap1 = *(const bf16x8*)&Ps[qh*32 + 16 + l15][kk*32 + quad*8];      \
      bf16x8 bv  = *(const bf16x8*)&Vs[ks*16 + l15][kk*32 + quad*8];           \
      acc[0] = mfma16(ap0, bv, acc[0]);                                        \
      acc[1] = mfma16(ap1, bv, acc[1]);                                        \
    }                                                                          \
    __builtin_amdgcn_s_setprio(0);                                             \
  }

  for (int kt2 = 0; kt2 < 16; kt2 += 2){
    ATTN_BODY(kt2,     ka0,ka1, va0,va1, kb0,kb1, vb0,vb1)
    ATTN_BODY(kt2 + 1, kb0,kb1, vb0,vb1, ka0,ka1, va0,va1)
  }
#undef ATTN_BODY

  // ---- epilogue: 4-way lsum combine only (O is fully summed per wave) ----
  #pragma unroll
  for (int mt = 0; mt < 2; ++mt){
    float v = lsum[mt];
    v += __shfl_xor(v, 16);
    v += __shfl_xor(v, 32);
    if (quad == 0) lsum_s[ks][qh*32 + mt*16 + l15] = v;
  }
  __syncthreads();

  #pragma unroll
  for (int mt = 0; mt < 2; ++mt){
    #pragma unroll
    for (int r = 0; r < 4; ++r){
      int ql = qh*32 + mt*16 + quad*4 + r;
      float tot = (lsum_s[0][ql] + lsum_s[1][ql])
                + (lsum_s[2][ql] + lsum_s[3][ql]);
      float inv = __builtin_amdgcn_rcpf(tot);
      Out[(size_t)(b*SEQ + q0 + ql)*EMBED + h*HD + ks*16 + l15]
        = (bf16)(acc[mt][r] * inv);
    }
  }
}

// ---------------- launch ----------------
extern "C" void kernel_launch(void* const* d_in, const int* in_sizes, int n_in,
                              void* d_out, int out_size, void* d_ws, size_t ws_size,
                              hipStream_t stream)
{
  (void)in_sizes; (void)n_in; (void)out_size;
  const float* Q  = (const float*)d_in[0];
  const float* K  = (const float*)d_in[1];
  const float* V  = (const float*)d_in[2];
  const int*   ID = (const int*)d_in[3];
  const float* Wq = (const float*)d_in[4];
  const float* Wk = (const float*)d_in[5];
  const float* Wv = (const float*)d_in[6];
  const float* Wo = (const float*)d_in[7];
  const float* RE = (const float*)d_in[8];
  float* out = (float*)d_out;

  const size_t MB = (size_t)1 << 20;
  if (ws_size < 36*MB) return;
  char* ws = (char*)d_ws;
  bf16*  Qb    = (bf16*)(ws + 0*MB);             // dead after proj -> AO overlay
  bf16*  Kb    = (bf16*)(ws + 4*MB);
  bf16*  Vb    = (bf16*)(ws + 8*MB);
  bf16*  Qp    = (bf16*)(ws + 12*MB);
  bf16*  Kp    = (bf16*)(ws + 16*MB);
  bf16*  Vt    = (bf16*)(ws + 20*MB);            // (b,h,d,s) written by proj z==2
  bf16*  Wall  = (bf16*)(ws + 24*MB);            // 2 MB (Wq',Wk',Wv',Wo')
  bf16*  Wop   = Wall + (size_t)3*262144;
  bf16*  Rb    = (bf16*)(ws + 26*MB);            // 48 KB
  bf16*  AO    = (bf16*)(ws + 0*MB);             // overlays Qb

  k_prep      <<<dim3(8032),    256, 0, stream>>>(Q, K, V, Wq, Wk, Wv, Wo, RE,
                                                  Qb, Kb, Vb, Wall, Rb);
  k_proj      <<<dim3(4,32,3),  256, 0, stream>>>(Qb, Kb, Vb, Wall, Qp, Kp, Vt);
  k_attn      <<<dim3(32,8,2),  512, 0, stream>>>(Qp, Kp, Vt, Rb, ID, AO);
  k_gemm_out  <<<dim3(4,32),    256, 0, stream>>>(AO, Wop, out);
}

// Round 15
// 217.123 us; speedup vs baseline: 1.0002x; 1.0002x over previous
//
#include <hip/hip_runtime.h>
#include <cstdint>
#include <cstddef>

#define SEQ   2048
#define BBAT  2
#define EMBED 512
#define NH    8
#define HD    64
#define NPOS  34

typedef __bf16 bf16;
typedef __bf16 bf16x8 __attribute__((ext_vector_type(8)));
typedef float  f32x4  __attribute__((ext_vector_type(4)));
typedef int    int32x4 __attribute__((ext_vector_type(4)));

// scale = log2(e)/8 : energy=(qk+bias)/8, computed in exp2 domain.
// ESCALE is folded into Qp at the projection epilogue (z==0).
#define ESCALE 0.1803368801111204f

__device__ __forceinline__ f32x4 mfma16(bf16x8 a, bf16x8 b, f32x4 c){
  return __builtin_amdgcn_mfma_f32_16x16x32_bf16(a, b, c, 0, 0, 0);
}

// lgkm-only barrier: does NOT drain vmcnt, so prefetch global loads stay in
// flight across it. sched_barrier(0) pins LDS ops on the correct side.
__device__ __forceinline__ void barrier_lgkm(){
  asm volatile("s_waitcnt lgkmcnt(0)" ::: "memory");
  __builtin_amdgcn_s_barrier();
  __builtin_amdgcn_sched_barrier(0);
}

// ---------------- kernel 1: fused prep (verbatim R4/R7) ----------------
__global__ __launch_bounds__(256) void k_prep(
    const float* __restrict__ Q, const float* __restrict__ K, const float* __restrict__ V,
    const float* __restrict__ Wq, const float* __restrict__ Wk,
    const float* __restrict__ Wv, const float* __restrict__ Wo,
    const float* __restrict__ RE,
    bf16* __restrict__ Qb, bf16* __restrict__ Kb, bf16* __restrict__ Vb,
    bf16* __restrict__ Wall, bf16* __restrict__ Rb)
{
  const int NCONV = 3*524288;
  const int NW = 196608, NO = 262144;
  int i = blockIdx.x*256 + threadIdx.x;
  if (i < NCONV){
    int tsel = i >> 19, j = i & 524287;
    const float* s = tsel==0 ? Q : (tsel==1 ? K : V);
    bf16* d       = tsel==0 ? Qb : (tsel==1 ? Kb : Vb);
    float4 v = ((const float4*)s)[j];
    union { bf16 e[4]; ushort4 u; } pk;
    pk.e[0]=(bf16)v.x; pk.e[1]=(bf16)v.y; pk.e[2]=(bf16)v.z; pk.e[3]=(bf16)v.w;
    ((ushort4*)d)[j] = pk.u;
  } else {
    int j = i - NCONV;
    if (j < NW){
      int w  = j >> 16;
      int r  = j & 65535;
      int np = r >> 7, c4 = (r & 127) << 2;
      const float* W = (w==0) ? Wq : ((w==1) ? Wk : Wv);
      int src = ((np & 63) << 3) + (np >> 6);
      float4 v = *(const float4*)(W + (size_t)src*512 + c4);
      union { bf16 e[4]; ushort4 u; } pk;
      pk.e[0]=(bf16)v.x; pk.e[1]=(bf16)v.y; pk.e[2]=(bf16)v.z; pk.e[3]=(bf16)v.w;
      *(ushort4*)(Wall + (size_t)w*262144 + (size_t)np*512 + c4) = pk.u;
    } else if (j < NW + NO){
      int jj = j - NW;
      int n = jj >> 9, kp = jj & 511;
      int src = ((kp & 63) << 3) + (kp >> 6);
      Wall[(size_t)3*262144 + (size_t)n*512 + kp] = (bf16)Wo[(size_t)n*512 + src];
    } else {
      int jj = j - NW - NO;
      if (jj < 8*48*64){
        int h  = jj / (48*64);
        int r2 = jj - h*(48*64);
        int p  = r2 >> 6, dd = r2 & 63;
        float v = (p < NPOS) ? RE[(size_t)p*512 + dd*8 + h] : 0.f;
        Rb[jj] = (bf16)v;
      }
    }
  }
}

// ---------------- kernel 2: projections, 128x128 tile, reg-dbuf pipelined (verbatim R7) ----------------
__global__ __launch_bounds__(256,2) void k_proj(
    const bf16* __restrict__ Qb, const bf16* __restrict__ Kb, const bf16* __restrict__ Vb,
    const bf16* __restrict__ W,
    bf16* __restrict__ Qp, bf16* __restrict__ Kp, bf16* __restrict__ Vt)
{
  const int z = blockIdx.z;
  const bf16* A  = z==0 ? Qb : (z==1 ? Kb : Vb);
  const bf16* Bw = W + (size_t)z*262144;

  __shared__ __align__(16) bf16 AB[2][128][72];
  bf16 (*As)[72] = AB[0];
  bf16 (*Bs)[72] = AB[1];

  const int t = threadIdx.x;
  const int w = t >> 6, lane = t & 63, l15 = lane & 15, quad = lane >> 4;
  const int wm = (w & 1) * 64, wn = (w >> 1) * 64;
  const int m0 = blockIdx.y * 128, n0 = blockIdx.x * 128;
  const int row = t >> 3, c8 = (t & 7) << 3;

  const bf16* Abase = A  + (size_t)(m0 + row)*512 + c8;
  const bf16* Bbase = Bw + (size_t)(n0 + row)*512 + c8;

  uint4 pa0,pa1,pa2,pa3, pb0,pb1,pb2,pb3;
  uint4 qa0,qa1,qa2,qa3, qb0,qb1,qb2,qb3;
  pa0 = *(const uint4*)(Abase);
  pa1 = *(const uint4*)(Abase + 32*512);
  pa2 = *(const uint4*)(Abase + 64*512);
  pa3 = *(const uint4*)(Abase + 96*512);
  pb0 = *(const uint4*)(Bbase);
  pb1 = *(const uint4*)(Bbase + 32*512);
  pb2 = *(const uint4*)(Bbase + 64*512);
  pb3 = *(const uint4*)(Bbase + 96*512);

  f32x4 acc[4][4];
  #pragma unroll
  for (int mt=0; mt<4; ++mt)
    #pragma unroll
    for (int nt=0; nt<4; ++nt) acc[mt][nt] = (f32x4){0.f,0.f,0.f,0.f};

#define PROJ_BODY(KT, A0,A1,A2,A3, B0,B1,B2,B3, LA0,LA1,LA2,LA3, LB0,LB1,LB2,LB3) \
  {                                                                             \
    barrier_lgkm();                                                             \
    *(uint4*)&As[row     ][c8] = A0;                                            \
    *(uint4*)&As[row + 32][c8] = A1;                                            \
    *(uint4*)&As[row + 64][c8] = A2;                                            \
    *(uint4*)&As[row + 96][c8] = A3;                                            \
    *(uint4*)&Bs[row     ][c8] = B0;                                            \
    *(uint4*)&Bs[row + 32][c8] = B1;                                            \
    *(uint4*)&Bs[row + 64][c8] = B2;                                            \
    *(uint4*)&Bs[row + 96][c8] = B3;                                            \
    if ((KT) < 7){                                                              \
      const bf16* ap2 = Abase + ((KT)+1)*64;                                    \
      const bf16* bp2 = Bbase + ((KT)+1)*64;                                    \
      LA0 = *(const uint4*)(ap2);                                               \
      LA1 = *(const uint4*)(ap2 + 32*512);                                      \
      LA2 = *(const uint4*)(ap2 + 64*512);                                      \
      LA3 = *(const uint4*)(ap2 + 96*512);                                      \
      LB0 = *(const uint4*)(bp2);                                               \
      LB1 = *(const uint4*)(bp2 + 32*512);                                      \
      LB2 = *(const uint4*)(bp2 + 64*512);                                      \
      LB3 = *(const uint4*)(bp2 + 96*512);                                      \
    }                                                                           \
    barrier_lgkm();                                                             \
    __builtin_amdgcn_s_setprio(1);                                              \
    _Pragma("unroll")                                                           \
    for (int ks = 0; ks < 2; ++ks){                                             \
      bf16x8 am[4], bn[4];                                                      \
      _Pragma("unroll")                                                         \
      for (int x=0;x<4;++x) am[x] = *(const bf16x8*)&As[wm + x*16 + l15][ks*32 + quad*8]; \
      _Pragma("unroll")                                                         \
      for (int y=0;y<4;++y) bn[y] = *(const bf16x8*)&Bs[wn + y*16 + l15][ks*32 + quad*8]; \
      _Pragma("unroll")                                                         \
      for (int mt=0;mt<4;++mt)                                                  \
        _Pragma("unroll")                                                       \
        for (int nt=0;nt<4;++nt)                                                \
          acc[mt][nt] = mfma16(am[mt], bn[nt], acc[mt][nt]);                    \
    }                                                                           \
    __builtin_amdgcn_s_setprio(0);                                              \
  }

  for (int kt2 = 0; kt2 < 8; kt2 += 2){
    PROJ_BODY(kt2,     pa0,pa1,pa2,pa3, pb0,pb1,pb2,pb3, qa0,qa1,qa2,qa3, qb0,qb1,qb2,qb3)
    PROJ_BODY(kt2 + 1, qa0,qa1,qa2,qa3, qb0,qb1,qb2,qb3, pa0,pa1,pa2,pa3, pb0,pb1,pb2,pb3)
  }
#undef PROJ_BODY

  if (z != 2){
    bf16* C = z==0 ? Qp : Kp;
    const float scl = (z==0) ? ESCALE : 1.0f;
    #pragma unroll
    for (int mt=0;mt<4;++mt)
      #pragma unroll
      for (int r=0;r<4;++r){
        int m = m0 + wm + mt*16 + quad*4 + r;
        #pragma unroll
        for (int nt=0;nt<4;++nt)
          C[(size_t)m*512 + n0 + wn + nt*16 + l15] = (bf16)(acc[mt][nt][r] * scl);
      }
  } else {
    __syncthreads();
    bf16 (*VT)[136] = (bf16(*)[136])AB;
    #pragma unroll
    for (int mt=0;mt<4;++mt)
      #pragma unroll
      for (int r=0;r<4;++r){
        int m = wm + mt*16 + quad*4 + r;
        #pragma unroll
        for (int nt=0;nt<4;++nt)
          VT[wn + nt*16 + l15][m] = (bf16)acc[mt][nt][r];
      }
    __syncthreads();
    const int b = m0 >> 11, s0 = m0 & 2047;
    const int n = t >> 1, c0 = (t & 1) * 64;
    const int h = blockIdx.x*2 + (n >> 6), d = n & 63;
    bf16* dst = Vt + ((size_t)((b*NH + h)*HD + d))*SEQ + s0 + c0;
    #pragma unroll
    for (int i = 0; i < 8; ++i)
      *(uint4*)(dst + i*8) = *(const uint4*)&VT[n][c0 + i*8];
  }
}

// ---------------- kernel 4: output projection, 128x128 tile, same pipeline (verbatim R7) ----------------
__global__ __launch_bounds__(256,2) void k_gemm_out(
    const bf16* __restrict__ A, const bf16* __restrict__ Bw, float* __restrict__ C)
{
  __shared__ __align__(16) bf16 AB[2][128][72];
  bf16 (*As)[72] = AB[0];
  bf16 (*Bs)[72] = AB[1];

  const int t = threadIdx.x;
  const int w = t >> 6, lane = t & 63, l15 = lane & 15, quad = lane >> 4;
  const int wm = (w & 1) * 64, wn = (w >> 1) * 64;
  const int m0 = blockIdx.y * 128, n0 = blockIdx.x * 128;
  const int row = t >> 3, c8 = (t & 7) << 3;

  const bf16* Abase = A  + (size_t)(m0 + row)*512 + c8;
  const bf16* Bbase = Bw + (size_t)(n0 + row)*512 + c8;

  uint4 pa0,pa1,pa2,pa3, pb0,pb1,pb2,pb3;
  uint4 qa0,qa1,qa2,qa3, qb0,qb1,qb2,qb3;
  pa0 = *(const uint4*)(Abase);
  pa1 = *(const uint4*)(Abase + 32*512);
  pa2 = *(const uint4*)(Abase + 64*512);
  pa3 = *(const uint4*)(Abase + 96*512);
  pb0 = *(const uint4*)(Bbase);
  pb1 = *(const uint4*)(Bbase + 32*512);
  pb2 = *(const uint4*)(Bbase + 64*512);
  pb3 = *(const uint4*)(Bbase + 96*512);

  f32x4 acc[4][4];
  #pragma unroll
  for (int mt=0; mt<4; ++mt)
    #pragma unroll
    for (int nt=0; nt<4; ++nt) acc[mt][nt] = (f32x4){0.f,0.f,0.f,0.f};

#define OUT_BODY(KT, A0,A1,A2,A3, B0,B1,B2,B3, LA0,LA1,LA2,LA3, LB0,LB1,LB2,LB3) \
  {                                                                             \
    barrier_lgkm();                                                             \
    *(uint4*)&As[row     ][c8] = A0;                                            \
    *(uint4*)&As[row + 32][c8] = A1;                                            \
    *(uint4*)&As[row + 64][c8] = A2;                                            \
    *(uint4*)&As[row + 96][c8] = A3;                                            \
    *(uint4*)&Bs[row     ][c8] = B0;                                            \
    *(uint4*)&Bs[row + 32][c8] = B1;                                            \
    *(uint4*)&Bs[row + 64][c8] = B2;                                            \
    *(uint4*)&Bs[row + 96][c8] = B3;                                            \
    if ((KT) < 7){                                                              \
      const bf16* ap2 = Abase + ((KT)+1)*64;                                    \
      const bf16* bp2 = Bbase + ((KT)+1)*64;                                    \
      LA0 = *(const uint4*)(ap2);                                               \
      LA1 = *(const uint4*)(ap2 + 32*512);                                      \
      LA2 = *(const uint4*)(ap2 + 64*512);                                      \
      LA3 = *(const uint4*)(ap2 + 96*512);                                      \
      LB0 = *(const uint4*)(bp2);                                               \
      LB1 = *(const uint4*)(bp2 + 32*512);                                      \
      LB2 = *(const uint4*)(bp2 + 64*512);                                      \
      LB3 = *(const uint4*)(bp2 + 96*512);                                      \
    }                                                                           \
    barrier_lgkm();                                                             \
    __builtin_amdgcn_s_setprio(1);                                              \
    _Pragma("unroll")                                                           \
    for (int ks = 0; ks < 2; ++ks){                                             \
      bf16x8 am[4], bn[4];                                                      \
      _Pragma("unroll")                                                         \
      for (int x=0;x<4;++x) am[x] = *(const bf16x8*)&As[wm + x*16 + l15][ks*32 + quad*8]; \
      _Pragma("unroll")                                                         \
      for (int y=0;y<4;++y) bn[y] = *(const bf16x8*)&Bs[wn + y*16 + l15][ks*32 + quad*8]; \
      _Pragma("unroll")                                                         \
      for (int mt=0;mt<4;++mt)                                                  \
        _Pragma("unroll")                                                       \
        for (int nt=0;nt<4;++nt)                                                \
          acc[mt][nt] = mfma16(am[mt], bn[nt], acc[mt][nt]);                    \
    }                                                                           \
    __builtin_amdgcn_s_setprio(0);                                              \
  }

  for (int kt2 = 0; kt2 < 8; kt2 += 2){
    OUT_BODY(kt2,     pa0,pa1,pa2,pa3, pb0,pb1,pb2,pb3, qa0,qa1,qa2,qa3, qb0,qb1,qb2,qb3)
    OUT_BODY(kt2 + 1, qa0,qa1,qa2,qa3, qb0,qb1,qb2,qb3, pa0,pa1,pa2,pa3, pb0,pb1,pb2,pb3)
  }
#undef OUT_BODY

  #pragma unroll
  for (int mt=0;mt<4;++mt)
    #pragma unroll
    for (int r=0;r<4;++r){
      int m = m0 + wm + mt*16 + quad*4 + r;
      #pragma unroll
      for (int nt=0;nt<4;++nt)
        C[(size_t)m*512 + n0 + wn + nt*16 + l15] = acc[mt][nt][r];
    }
}

// ---------------- kernel 3: flash attention v10 -- v9 8-wave with allocator PINNED ----------------
// R14: launch_bounds(512,4) let the allocator target 8 waves/EU (64 VGPR) and
// spill ~50 regs (WRITE 136MB) chasing an occupancy LDS makes impossible
// (63.5KB -> max 2 WG/CU = 4 waves/EU). Occupancy DID rise 17->38% proving
// the G1 mechanism. v10: pin amdgpu_waves_per_eu(4,4) -> 128-VGPR budget,
// true need ~116 -> no spill. Everything else identical to v9.
__global__ __launch_bounds__(512) __attribute__((amdgpu_waves_per_eu(4,4)))
void k_attn(
    const bf16* __restrict__ Qp, const bf16* __restrict__ Kp,
    const bf16* __restrict__ Vt, const bf16* __restrict__ Rb,
    const int* __restrict__ ids, bf16* __restrict__ Out)
{
  // LDS: 18432 + 17408 + 17408 + 9100 + 1024 = 63372 B -> 2 WG/CU (16 waves)
  __shared__ __align__(16) bf16 Ks[128][72];
  __shared__ __align__(16) bf16 Vs[64][136];
  __shared__ __align__(16) bf16 Ps[64][136];
  __shared__ float lutT[35][65];
  __shared__ float lsum_s[4][64];

  const int t = threadIdx.x;                    // 0..511
  const int b = blockIdx.z, h = blockIdx.y;
  const int q0 = blockIdx.x * 64;
  const int w = t >> 6;                         // 0..7
  const int lane = t & 63, l15 = lane & 15, quad = lane >> 4;
  const int qh = w & 1, ks = w >> 1;            // ks: QK k-chunk AND PV d-chunk

  const size_t idb = (size_t)b*SEQ*SEQ;
  const bf16* kbase = Kp + (size_t)b*SEQ*EMBED + h*HD;
  const bf16* vbase = Vt + (size_t)(b*NH + h)*HD*SEQ;

  // staging geometry (512 threads): K rows krow/krow+64 ; V rows vrow/vrow+32
  const int krow = t >> 3, kcol = (t & 7) << 3;
  const int vrow = t >> 4, vcol = (t & 15) << 3;

  uint4 ka0, ka1, va0, va1;
  uint4 kb0, kb1, vb0, vb1;
  ka0 = *(const uint4*)(kbase + (size_t)(krow     )*EMBED + kcol);
  ka1 = *(const uint4*)(kbase + (size_t)(krow + 64)*EMBED + kcol);
  va0 = *(const uint4*)(vbase + (size_t)(vrow     )*SEQ + vcol);
  va1 = *(const uint4*)(vbase + (size_t)(vrow + 32)*SEQ + vcol);

  // ---- prefetch tile-0 ids: q = qh*32+mt*16+l15, k = ks*32+nt*16+quad*4 ----
  int32x4 nid[2][2];
  #pragma unroll
  for (int mt=0; mt<2; ++mt)
    #pragma unroll
    for (int nt=0; nt<2; ++nt)
      nid[mt][nt] = *(const int32x4*)(ids + idb
          + (size_t)(q0 + qh*32 + mt*16 + l15)*SEQ
          + ks*32 + nt*16 + quad*4);

  // ---- build LUT via MFMA (waves 0-3 only; rows are in-tile there) ----
  if (w < 4){
    const bf16* qbrow = Qp + (size_t)(b*SEQ + q0 + w*16 + l15)*EMBED + h*HD;
    bf16x8 ab0 = *(const bf16x8*)(qbrow + quad*8);
    bf16x8 ab1 = *(const bf16x8*)(qbrow + 32 + quad*8);
    const bf16* rh = Rb + h*3072;
    #pragma unroll
    for (int nt = 0; nt < 3; ++nt){
      bf16x8 r0 = *(const bf16x8*)(rh + (nt*16 + l15)*64 + quad*8);
      bf16x8 r1 = *(const bf16x8*)(rh + (nt*16 + l15)*64 + 32 + quad*8);
      f32x4 c = (f32x4){0.f,0.f,0.f,0.f};
      c = mfma16(ab0, r0, c);
      c = mfma16(ab1, r1, c);
      int p = nt*16 + l15;
      if (p < NPOS){
        #pragma unroll
        for (int r = 0; r < 4; ++r)
          lutT[p][w*16 + quad*4 + r] = (p == 0) ? -1e30f : c[r];
      }
    }
  }

  // ---- QK B-frags (Q rows, reg-resident) ----
  bf16x8 bq[2][2];
  #pragma unroll
  for (int mt = 0; mt < 2; ++mt){
    const bf16* qrow = Qp + (size_t)(b*SEQ + q0 + qh*32 + mt*16 + l15)*EMBED + h*HD;
    bq[mt][0] = *(const bf16x8*)(qrow + quad*8);
    bq[mt][1] = *(const bf16x8*)(qrow + 32 + quad*8);
  }

  __syncthreads();   // lutT visible to all 8 waves

  f32x4 acc[2];
  acc[0] = (f32x4){0.f,0.f,0.f,0.f};
  acc[1] = (f32x4){0.f,0.f,0.f,0.f};
  float lsum[2] = {0.f, 0.f};

#define ATTN_BODY(KT, K0,K1, V0,V1, L0,L1, M0,M1)                              \
  {                                                                            \
    barrier_lgkm();  /* B1: all waves done with Ks/Vs/Ps of prev tile */       \
    *(uint4*)&Ks[krow     ][kcol] = K0;                                        \
    *(uint4*)&Ks[krow + 64][kcol] = K1;                                        \
    *(uint4*)&Vs[vrow     ][vcol] = V0;                                        \
    *(uint4*)&Vs[vrow + 32][vcol] = V1;                                        \
    if ((KT) < 15){                                                            \
      const bf16* kp2 = kbase + (size_t)(((KT)+1)*128)*EMBED + kcol;           \
      const bf16* vp2 = vbase + ((KT)+1)*128 + vcol;                           \
      L0 = *(const uint4*)(kp2 + (size_t)(krow     )*EMBED);                   \
      L1 = *(const uint4*)(kp2 + (size_t)(krow + 64)*EMBED);                   \
      M0 = *(const uint4*)(vp2 + (size_t)(vrow     )*SEQ);                     \
      M1 = *(const uint4*)(vp2 + (size_t)(vrow + 32)*SEQ);                     \
    }                                                                          \
    barrier_lgkm();  /* B2: staged tile ready; prefetch loads keep flying */   \
    float wvv[2][2][4];                                                        \
    _Pragma("unroll")                                                          \
    for (int mt = 0; mt < 2; ++mt){                                            \
      const float* lcol = &lutT[0][qh*32 + mt*16 + l15];                       \
      _Pragma("unroll")                                                        \
      for (int nt = 0; nt < 2; ++nt){                                          \
        int32x4 v = nid[mt][nt];                                               \
        wvv[mt][nt][0] = lcol[v[0] * 65];                                      \
        wvv[mt][nt][1] = lcol[v[1] * 65];                                      \
        wvv[mt][nt][2] = lcol[v[2] * 65];                                      \
        wvv[mt][nt][3] = lcol[v[3] * 65];                                      \
      }                                                                        \
    }                                                                          \
    if ((KT) < 15){                                                            \
      _Pragma("unroll")                                                        \
      for (int mt = 0; mt < 2; ++mt)                                           \
        _Pragma("unroll")                                                      \
        for (int nt = 0; nt < 2; ++nt)                                         \
          nid[mt][nt] = *(const int32x4*)(ids + idb                            \
              + (size_t)(q0 + qh*32 + mt*16 + l15)*SEQ                         \
              + (((KT)+1)*128) + ks*32 + nt*16 + quad*4);                      \
    }                                                                          \
    f32x4 sf[2][2];                                                            \
    __builtin_amdgcn_s_setprio(1);                                             \
    _Pragma("unroll")                                                          \
    for (int nt = 0; nt < 2; ++nt){                                            \
      bf16x8 ak0 = *(const bf16x8*)&Ks[ks*32 + nt*16 + l15][quad*8];           \
      bf16x8 ak1 = *(const bf16x8*)&Ks[ks*32 + nt*16 + l15][32 + quad*8];      \
      _Pragma("unroll")                                                        \
      for (int mt = 0; mt < 2; ++mt){                                          \
        f32x4 c = (f32x4){0.f,0.f,0.f,0.f};                                    \
        c = mfma16(ak0, bq[mt][0], c);                                         \
        c = mfma16(ak1, bq[mt][1], c);                                         \
        sf[mt][nt] = c;                                                        \
      }                                                                        \
    }                                                                          \
    __builtin_amdgcn_s_setprio(0);                                             \
    _Pragma("unroll")                                                          \
    for (int mt = 0; mt < 2; ++mt){                                            \
      _Pragma("unroll")                                                        \
      for (int nt = 0; nt < 2; ++nt){                                          \
        union { bf16 e[4]; uint2 u; } pk;                                      \
        float p0 = __builtin_amdgcn_exp2f(sf[mt][nt][0] + wvv[mt][nt][0]);     \
        float p1 = __builtin_amdgcn_exp2f(sf[mt][nt][1] + wvv[mt][nt][1]);     \
        float p2 = __builtin_amdgcn_exp2f(sf[mt][nt][2] + wvv[mt][nt][2]);     \
        float p3 = __builtin_amdgcn_exp2f(sf[mt][nt][3] + wvv[mt][nt][3]);     \
        pk.e[0] = (bf16)p0; pk.e[1] = (bf16)p1;                                \
        pk.e[2] = (bf16)p2; pk.e[3] = (bf16)p3;                                \
        lsum[mt] += (p0 + p1) + (p2 + p3);                                     \
        *(uint2*)&Ps[qh*32 + mt*16 + l15][ks*32 + nt*16 + quad*4] = pk.u;      \
      }                                                                        \
    }                                                                          \
    barrier_lgkm();  /* B3: Ps complete (cross-wave) */                        \
    __builtin_amdgcn_s_setprio(1);                                             \
    _Pragma("unroll")                                                          \
    for (int kk = 0; kk < 4; ++kk){                                            \
      bf16x8 ap0 = *(const bf16x8*)&Ps[qh*32      + l15][kk*32 + quad*8];      \
      bf16x8 ap1 = *(const bf16x8*)&Ps[qh*32 + 16 + l15][kk*32 + quad*8];      \
      bf16x8 bv  = *(const bf16x8*)&Vs[ks*16 + l15][kk*32 + quad*8];           \
      acc[0] = mfma16(ap0, bv, acc[0]);                                        \
      acc[1] = mfma16(ap1, bv, acc[1]);                                        \
    }                                                                          \
    __builtin_amdgcn_s_setprio(0);                                             \
  }

  for (int kt2 = 0; kt2 < 16; kt2 += 2){
    ATTN_BODY(kt2,     ka0,ka1, va0,va1, kb0,kb1, vb0,vb1)
    ATTN_BODY(kt2 + 1, kb0,kb1, vb0,vb1, ka0,ka1, va0,va1)
  }
#undef ATTN_BODY

  // ---- epilogue: 4-way lsum combine only (O is fully summed per wave) ----
  #pragma unroll
  for (int mt = 0; mt < 2; ++mt){
    float v = lsum[mt];
    v += __shfl_xor(v, 16);
    v += __shfl_xor(v, 32);
    if (quad == 0) lsum_s[ks][qh*32 + mt*16 + l15] = v;
  }
  __syncthreads();

  #pragma unroll
  for (int mt = 0; mt < 2; ++mt){
    #pragma unroll
    for (int r = 0; r < 4; ++r){
      int ql = qh*32 + mt*16 + quad*4 + r;
      float tot = (lsum_s[0][ql] + lsum_s[1][ql])
                + (lsum_s[2][ql] + lsum_s[3][ql]);
      float inv = __builtin_amdgcn_rcpf(tot);
      Out[(size_t)(b*SEQ + q0 + ql)*EMBED + h*HD + ks*16 + l15]
        = (bf16)(acc[mt][r] * inv);
    }
  }
}

// ---------------- launch ----------------
extern "C" void kernel_launch(void* const* d_in, const int* in_sizes, int n_in,
                              void* d_out, int out_size, void* d_ws, size_t ws_size,
                              hipStream_t stream)
{
  (void)in_sizes; (void)n_in; (void)out_size;
  const float* Q  = (const float*)d_in[0];
  const float* K  = (const float*)d_in[1];
  const float* V  = (const float*)d_in[2];
  const int*   ID = (const int*)d_in[3];
  const float* Wq = (const float*)d_in[4];
  const float* Wk = (const float*)d_in[5];
  const float* Wv = (const float*)d_in[6];
  const float* Wo = (const float*)d_in[7];
  const float* RE = (const float*)d_in[8];
  float* out = (float*)d_out;

  const size_t MB = (size_t)1 << 20;
  if (ws_size < 36*MB) return;
  char* ws = (char*)d_ws;
  bf16*  Qb    = (bf16*)(ws + 0*MB);             // dead after proj -> AO overlay
  bf16*  Kb    = (bf16*)(ws + 4*MB);
  bf16*  Vb    = (bf16*)(ws + 8*MB);
  bf16*  Qp    = (bf16*)(ws + 12*MB);
  bf16*  Kp    = (bf16*)(ws + 16*MB);
  bf16*  Vt    = (bf16*)(ws + 20*MB);            // (b,h,d,s) written by proj z==2
  bf16*  Wall  = (bf16*)(ws + 24*MB);            // 2 MB (Wq',Wk',Wv',Wo')
  bf16*  Wop   = Wall + (size_t)3*262144;
  bf16*  Rb    = (bf16*)(ws + 26*MB);            // 48 KB
  bf16*  AO    = (bf16*)(ws + 0*MB);             // overlays Qb

  k_prep      <<<dim3(8032),    256, 0, stream>>>(Q, K, V, Wq, Wk, Wv, Wo, RE,
                                                  Qb, Kb, Vb, Wall, Rb);
  k_proj      <<<dim3(4,32,3),  256, 0, stream>>>(Qb, Kb, Vb, Wall, Qp, Kp, Vt);
  k_attn      <<<dim3(32,8,2),  512, 0, stream>>>(Qp, Kp, Vt, Rb, ID, AO);
  k_gemm_out  <<<dim3(4,32),    256, 0, stream>>>(AO, Wop, out);
}

// Round 19
// 177.764 us; speedup vs baseline: 1.2216x; 1.2214x over previous
//
#include <hip/hip_runtime.h>
#include <cstdint>
#include <cstddef>

#define SEQ   2048
#define BBAT  2
#define EMBED 512
#define NH    8
#define HD    64
#define NPOS  34

typedef __bf16 bf16;
typedef __bf16 bf16x8 __attribute__((ext_vector_type(8)));
typedef float  f32x4  __attribute__((ext_vector_type(4)));
typedef int    int32x4 __attribute__((ext_vector_type(4)));

// scale = log2(e)/8 : energy=(qk+bias)/8, computed in exp2 domain.
// ESCALE is folded into Qp at the projection epilogue (z==0).
#define ESCALE 0.1803368801111204f

__device__ __forceinline__ f32x4 mfma16(bf16x8 a, bf16x8 b, f32x4 c){
  return __builtin_amdgcn_mfma_f32_16x16x32_bf16(a, b, c, 0, 0, 0);
}

// lgkm-only barrier: does NOT drain vmcnt, so prefetch global loads stay in
// flight across it. sched_barrier(0) pins LDS ops on the correct side.
__device__ __forceinline__ void barrier_lgkm(){
  asm volatile("s_waitcnt lgkmcnt(0)" ::: "memory");
  __builtin_amdgcn_s_barrier();
  __builtin_amdgcn_sched_barrier(0);
}

// ---------------- kernel 1: fused prep ----------------
__global__ __launch_bounds__(256) void k_prep(
    const float* __restrict__ Q, const float* __restrict__ K, const float* __restrict__ V,
    const float* __restrict__ Wq, const float* __restrict__ Wk,
    const float* __restrict__ Wv, const float* __restrict__ Wo,
    const float* __restrict__ RE,
    bf16* __restrict__ Qb, bf16* __restrict__ Kb, bf16* __restrict__ Vb,
    bf16* __restrict__ Wall, bf16* __restrict__ Rb)
{
  const int NCONV = 3*524288;
  const int NW = 196608, NO = 262144;
  int i = blockIdx.x*256 + threadIdx.x;
  if (i < NCONV){
    int tsel = i >> 19, j = i & 524287;
    const float* s = tsel==0 ? Q : (tsel==1 ? K : V);
    bf16* d       = tsel==0 ? Qb : (tsel==1 ? Kb : Vb);
    float4 v = ((const float4*)s)[j];
    union { bf16 e[4]; ushort4 u; } pk;
    pk.e[0]=(bf16)v.x; pk.e[1]=(bf16)v.y; pk.e[2]=(bf16)v.z; pk.e[3]=(bf16)v.w;
    ((ushort4*)d)[j] = pk.u;
  } else {
    int j = i - NCONV;
    if (j < NW){
      int w  = j >> 16;
      int r  = j & 65535;
      int np = r >> 7, c4 = (r & 127) << 2;
      const float* W = (w==0) ? Wq : ((w==1) ? Wk : Wv);
      int src = ((np & 63) << 3) + (np >> 6);
      float4 v = *(const float4*)(W + (size_t)src*512 + c4);
      union { bf16 e[4]; ushort4 u; } pk;
      pk.e[0]=(bf16)v.x; pk.e[1]=(bf16)v.y; pk.e[2]=(bf16)v.z; pk.e[3]=(bf16)v.w;
      *(ushort4*)(Wall + (size_t)w*262144 + (size_t)np*512 + c4) = pk.u;
    } else if (j < NW + NO){
      int jj = j - NW;
      int n = jj >> 9, kp = jj & 511;
      int src = ((kp & 63) << 3) + (kp >> 6);
      Wall[(size_t)3*262144 + (size_t)n*512 + kp] = (bf16)Wo[(size_t)n*512 + src];
    } else {
      int jj = j - NW - NO;
      if (jj < 8*48*64){
        int h  = jj / (48*64);
        int r2 = jj - h*(48*64);
        int p  = r2 >> 6, dd = r2 & 63;
        float v = (p < NPOS) ? RE[(size_t)p*512 + dd*8 + h] : 0.f;
        Rb[jj] = (bf16)v;
      }
    }
  }
}

// ---------------- kernel 2: projections, 128x128 tile, reg-dbuf pipelined ----------------
__global__ __launch_bounds__(256,2) void k_proj(
    const bf16* __restrict__ Qb, const bf16* __restrict__ Kb, const bf16* __restrict__ Vb,
    const bf16* __restrict__ W,
    bf16* __restrict__ Qp, bf16* __restrict__ Kp, bf16* __restrict__ Vt)
{
  const int z = blockIdx.z;
  const bf16* A  = z==0 ? Qb : (z==1 ? Kb : Vb);
  const bf16* Bw = W + (size_t)z*262144;

  __shared__ __align__(16) bf16 AB[2][128][72];
  bf16 (*As)[72] = AB[0];
  bf16 (*Bs)[72] = AB[1];

  const int t = threadIdx.x;
  const int w = t >> 6, lane = t & 63, l15 = lane & 15, quad = lane >> 4;
  const int wm = (w & 1) * 64, wn = (w >> 1) * 64;
  const int m0 = blockIdx.y * 128, n0 = blockIdx.x * 128;
  const int row = t >> 3, c8 = (t & 7) << 3;

  const bf16* Abase = A  + (size_t)(m0 + row)*512 + c8;
  const bf16* Bbase = Bw + (size_t)(n0 + row)*512 + c8;

  uint4 pa0,pa1,pa2,pa3, pb0,pb1,pb2,pb3;
  uint4 qa0,qa1,qa2,qa3, qb0,qb1,qb2,qb3;
  pa0 = *(const uint4*)(Abase);
  pa1 = *(const uint4*)(Abase + 32*512);
  pa2 = *(const uint4*)(Abase + 64*512);
  pa3 = *(const uint4*)(Abase + 96*512);
  pb0 = *(const uint4*)(Bbase);
  pb1 = *(const uint4*)(Bbase + 32*512);
  pb2 = *(const uint4*)(Bbase + 64*512);
  pb3 = *(const uint4*)(Bbase + 96*512);

  f32x4 acc[4][4];
  #pragma unroll
  for (int mt=0; mt<4; ++mt)
    #pragma unroll
    for (int nt=0; nt<4; ++nt) acc[mt][nt] = (f32x4){0.f,0.f,0.f,0.f};

#define PROJ_BODY(KT, A0,A1,A2,A3, B0,B1,B2,B3, LA0,LA1,LA2,LA3, LB0,LB1,LB2,LB3) \
  {                                                                             \
    barrier_lgkm();                                                             \
    *(uint4*)&As[row     ][c8] = A0;                                            \
    *(uint4*)&As[row + 32][c8] = A1;                                            \
    *(uint4*)&As[row + 64][c8] = A2;                                            \
    *(uint4*)&As[row + 96][c8] = A3;                                            \
    *(uint4*)&Bs[row     ][c8] = B0;                                            \
    *(uint4*)&Bs[row + 32][c8] = B1;                                            \
    *(uint4*)&Bs[row + 64][c8] = B2;                                            \
    *(uint4*)&Bs[row + 96][c8] = B3;                                            \
    if ((KT) < 7){                                                              \
      const bf16* ap2 = Abase + ((KT)+1)*64;                                    \
      const bf16* bp2 = Bbase + ((KT)+1)*64;                                    \
      LA0 = *(const uint4*)(ap2);                                               \
      LA1 = *(const uint4*)(ap2 + 32*512);                                      \
      LA2 = *(const uint4*)(ap2 + 64*512);                                      \
      LA3 = *(const uint4*)(ap2 + 96*512);                                      \
      LB0 = *(const uint4*)(bp2);                                               \
      LB1 = *(const uint4*)(bp2 + 32*512);                                      \
      LB2 = *(const uint4*)(bp2 + 64*512);                                      \
      LB3 = *(const uint4*)(bp2 + 96*512);                                      \
    }                                                                           \
    barrier_lgkm();                                                             \
    __builtin_amdgcn_s_setprio(1);                                              \
    _Pragma("unroll")                                                           \
    for (int ks = 0; ks < 2; ++ks){                                             \
      bf16x8 am[4], bn[4];                                                      \
      _Pragma("unroll")                                                         \
      for (int x=0;x<4;++x) am[x] = *(const bf16x8*)&As[wm + x*16 + l15][ks*32 + quad*8]; \
      _Pragma("unroll")                                                         \
      for (int y=0;y<4;++y) bn[y] = *(const bf16x8*)&Bs[wn + y*16 + l15][ks*32 + quad*8]; \
      _Pragma("unroll")                                                         \
      for (int mt=0;mt<4;++mt)                                                  \
        _Pragma("unroll")                                                       \
        for (int nt=0;nt<4;++nt)                                                \
          acc[mt][nt] = mfma16(am[mt], bn[nt], acc[mt][nt]);                    \
    }                                                                           \
    __builtin_amdgcn_s_setprio(0);                                              \
  }

  for (int kt2 = 0; kt2 < 8; kt2 += 2){
    PROJ_BODY(kt2,     pa0,pa1,pa2,pa3, pb0,pb1,pb2,pb3, qa0,qa1,qa2,qa3, qb0,qb1,qb2,qb3)
    PROJ_BODY(kt2 + 1, qa0,qa1,qa2,qa3, qb0,qb1,qb2,qb3, pa0,pa1,pa2,pa3, pb0,pb1,pb2,pb3)
  }
#undef PROJ_BODY

  if (z != 2){
    bf16* C = z==0 ? Qp : Kp;
    const float scl = (z==0) ? ESCALE : 1.0f;
    #pragma unroll
    for (int mt=0;mt<4;++mt)
      #pragma unroll
      for (int r=0;r<4;++r){
        int m = m0 + wm + mt*16 + quad*4 + r;
        #pragma unroll
        for (int nt=0;nt<4;++nt)
          C[(size_t)m*512 + n0 + wn + nt*16 + l15] = (bf16)(acc[mt][nt][r] * scl);
      }
  } else {
    __syncthreads();
    bf16 (*VT)[136] = (bf16(*)[136])AB;
    #pragma unroll
    for (int mt=0;mt<4;++mt)
      #pragma unroll
      for (int r=0;r<4;++r){
        int m = wm + mt*16 + quad*4 + r;
        #pragma unroll
        for (int nt=0;nt<4;++nt)
          VT[wn + nt*16 + l15][m] = (bf16)acc[mt][nt][r];
      }
    __syncthreads();
    const int b = m0 >> 11, s0 = m0 & 2047;
    const int n = t >> 1, c0 = (t & 1) * 64;
    const int h = blockIdx.x*2 + (n >> 6), d = n & 63;
    bf16* dst = Vt + ((size_t)((b*NH + h)*HD + d))*SEQ + s0 + c0;
    #pragma unroll
    for (int i = 0; i < 8; ++i)
      *(uint4*)(dst + i*8) = *(const uint4*)&VT[n][c0 + i*8];
  }
}

// ---------------- kernel 4: output projection, 128x128 tile, same pipeline ----------------
__global__ __launch_bounds__(256,2) void k_gemm_out(
    const bf16* __restrict__ A, const bf16* __restrict__ Bw, float* __restrict__ C)
{
  __shared__ __align__(16) bf16 AB[2][128][72];
  bf16 (*As)[72] = AB[0];
  bf16 (*Bs)[72] = AB[1];

  const int t = threadIdx.x;
  const int w = t >> 6, lane = t & 63, l15 = lane & 15, quad = lane >> 4;
  const int wm = (w & 1) * 64, wn = (w >> 1) * 64;
  const int m0 = blockIdx.y * 128, n0 = blockIdx.x * 128;
  const int row = t >> 3, c8 = (t & 7) << 3;

  const bf16* Abase = A  + (size_t)(m0 + row)*512 + c8;
  const bf16* Bbase = Bw + (size_t)(n0 + row)*512 + c8;

  uint4 pa0,pa1,pa2,pa3, pb0,pb1,pb2,pb3;
  uint4 qa0,qa1,qa2,qa3, qb0,qb1,qb2,qb3;
  pa0 = *(const uint4*)(Abase);
  pa1 = *(const uint4*)(Abase + 32*512);
  pa2 = *(const uint4*)(Abase + 64*512);
  pa3 = *(const uint4*)(Abase + 96*512);
  pb0 = *(const uint4*)(Bbase);
  pb1 = *(const uint4*)(Bbase + 32*512);
  pb2 = *(const uint4*)(Bbase + 64*512);
  pb3 = *(const uint4*)(Bbase + 96*512);

  f32x4 acc[4][4];
  #pragma unroll
  for (int mt=0; mt<4; ++mt)
    #pragma unroll
    for (int nt=0; nt<4; ++nt) acc[mt][nt] = (f32x4){0.f,0.f,0.f,0.f};

#define OUT_BODY(KT, A0,A1,A2,A3, B0,B1,B2,B3, LA0,LA1,LA2,LA3, LB0,LB1,LB2,LB3) \
  {                                                                             \
    barrier_lgkm();                                                             \
    *(uint4*)&As[row     ][c8] = A0;                                            \
    *(uint4*)&As[row + 32][c8] = A1;                                            \
    *(uint4*)&As[row + 64][c8] = A2;                                            \
    *(uint4*)&As[row + 96][c8] = A3;                                            \
    *(uint4*)&Bs[row     ][c8] = B0;                                            \
    *(uint4*)&Bs[row + 32][c8] = B1;                                            \
    *(uint4*)&Bs[row + 64][c8] = B2;                                            \
    *(uint4*)&Bs[row + 96][c8] = B3;                                            \
    if ((KT) < 7){                                                              \
      const bf16* ap2 = Abase + ((KT)+1)*64;                                    \
      const bf16* bp2 = Bbase + ((KT)+1)*64;                                    \
      LA0 = *(const uint4*)(ap2);                                               \
      LA1 = *(const uint4*)(ap2 + 32*512);                                      \
      LA2 = *(const uint4*)(ap2 + 64*512);                                      \
      LA3 = *(const uint4*)(ap2 + 96*512);                                      \
      LB0 = *(const uint4*)(bp2);                                               \
      LB1 = *(const uint4*)(bp2 + 32*512);                                      \
      LB2 = *(const uint4*)(bp2 + 64*512);                                      \
      LB3 = *(const uint4*)(bp2 + 96*512);                                      \
    }                                                                           \
    barrier_lgkm();                                                             \
    __builtin_amdgcn_s_setprio(1);                                              \
    _Pragma("unroll")                                                           \
    for (int ks = 0; ks < 2; ++ks){                                             \
      bf16x8 am[4], bn[4];                                                      \
      _Pragma("unroll")                                                         \
      for (int x=0;x<4;++x) am[x] = *(const bf16x8*)&As[wm + x*16 + l15][ks*32 + quad*8]; \
      _Pragma("unroll")                                                         \
      for (int y=0;y<4;++y) bn[y] = *(const bf16x8*)&Bs[wn + y*16 + l15][ks*32 + quad*8]; \
      _Pragma("unroll")                                                         \
      for (int mt=0;mt<4;++mt)                                                  \
        _Pragma("unroll")                                                       \
        for (int nt=0;nt<4;++nt)                                                \
          acc[mt][nt] = mfma16(am[mt], bn[nt], acc[mt][nt]);                    \
    }                                                                           \
    __builtin_amdgcn_s_setprio(0);                                              \
  }

  for (int kt2 = 0; kt2 < 8; kt2 += 2){
    OUT_BODY(kt2,     pa0,pa1,pa2,pa3, pb0,pb1,pb2,pb3, qa0,qa1,qa2,qa3, qb0,qb1,qb2,qb3)
    OUT_BODY(kt2 + 1, qa0,qa1,qa2,qa3, qb0,qb1,qb2,qb3, pa0,pa1,pa2,pa3, pb0,pb1,pb2,pb3)
  }
#undef OUT_BODY

  #pragma unroll
  for (int mt=0;mt<4;++mt)
    #pragma unroll
    for (int r=0;r<4;++r){
      int m = m0 + wm + mt*16 + quad*4 + r;
      #pragma unroll
      for (int nt=0;nt<4;++nt)
        C[(size_t)m*512 + n0 + wn + nt*16 + l15] = acc[mt][nt][r];
    }
}

// ---------------- kernel 3: flash attention (verbatim R7 v5, 58.5us verified) ----------------
__global__ __launch_bounds__(256,2) void k_attn(
    const bf16* __restrict__ Qp, const bf16* __restrict__ Kp,
    const bf16* __restrict__ Vt, const bf16* __restrict__ Rb,
    const int* __restrict__ ids, bf16* __restrict__ Out)
{
  // LDS: 18432 + 17408 + 17408 + 9100 + 512 = 62860 B -> 2 WG/CU
  __shared__ __align__(16) bf16 Ks[128][72];
  __shared__ __align__(16) bf16 Vs[64][136];
  __shared__ __align__(16) bf16 Ps[64][136];
  __shared__ float lutT[35][65];
  __shared__ float lsum_s[128];

  const int t = threadIdx.x;
  const int b = blockIdx.z, h = blockIdx.y;
  const int q0 = blockIdx.x * 64;
  const int w = t >> 6, lane = t & 63, l15 = lane & 15, quad = lane >> 4;
  const int qh = w & 1, kh = w >> 1;

  const size_t idb = (size_t)b*SEQ*SEQ;
  const bf16* kbase = Kp + (size_t)b*SEQ*EMBED + h*HD;
  const bf16* vbase = Vt + (size_t)(b*NH + h)*HD*SEQ;

  const int krow = t >> 3, kcol = (t & 7) << 3;
  const int vrow = t >> 4, vcol = (t & 15) << 3;

  uint4 ka0, ka1, ka2, ka3, va0, va1, va2, va3;
  uint4 kb0, kb1, kb2, kb3, vb0, vb1, vb2, vb3;
  ka0 = *(const uint4*)(kbase + (size_t)(krow     )*EMBED + kcol);
  ka1 = *(const uint4*)(kbase + (size_t)(krow + 32)*EMBED + kcol);
  ka2 = *(const uint4*)(kbase + (size_t)(krow + 64)*EMBED + kcol);
  ka3 = *(const uint4*)(kbase + (size_t)(krow + 96)*EMBED + kcol);
  va0 = *(const uint4*)(vbase + (size_t)(vrow     )*SEQ + vcol);
  va1 = *(const uint4*)(vbase + (size_t)(vrow + 16)*SEQ + vcol);
  va2 = *(const uint4*)(vbase + (size_t)(vrow + 32)*SEQ + vcol);
  va3 = *(const uint4*)(vbase + (size_t)(vrow + 48)*SEQ + vcol);

  int32x4 nid[2][4];
  #pragma unroll
  for (int mt=0; mt<2; ++mt)
    #pragma unroll
    for (int nt=0; nt<4; ++nt)
      nid[mt][nt] = *(const int32x4*)(ids + idb
          + (size_t)(q0 + qh*32 + mt*16 + l15)*SEQ
          + kh*64 + nt*16 + quad*4);

  {
    const bf16* qbrow = Qp + (size_t)(b*SEQ + q0 + w*16 + l15)*EMBED + h*HD;
    bf16x8 ab0 = *(const bf16x8*)(qbrow + quad*8);
    bf16x8 ab1 = *(const bf16x8*)(qbrow + 32 + quad*8);
    const bf16* rh = Rb + h*3072;
    #pragma unroll
    for (int nt = 0; nt < 3; ++nt){
      bf16x8 r0 = *(const bf16x8*)(rh + (nt*16 + l15)*64 + quad*8);
      bf16x8 r1 = *(const bf16x8*)(rh + (nt*16 + l15)*64 + 32 + quad*8);
      f32x4 c = (f32x4){0.f,0.f,0.f,0.f};
      c = mfma16(ab0, r0, c);
      c = mfma16(ab1, r1, c);
      int p = nt*16 + l15;
      if (p < NPOS){
        #pragma unroll
        for (int r = 0; r < 4; ++r)
          lutT[p][w*16 + quad*4 + r] = (p == 0) ? -1e30f : c[r];
      }
    }
  }

  bf16x8 bq[2][2];
  #pragma unroll
  for (int mt = 0; mt < 2; ++mt){
    const bf16* qrow = Qp + (size_t)(b*SEQ + q0 + qh*32 + mt*16 + l15)*EMBED + h*HD;
    bq[mt][0] = *(const bf16x8*)(qrow + quad*8);
    bq[mt][1] = *(const bf16x8*)(qrow + 32 + quad*8);
  }

  f32x4 acc[2][4];
  #pragma unroll
  for (int mt=0;mt<2;++mt)
    #pragma unroll
    for (int nt=0;nt<4;++nt) acc[mt][nt] = (f32x4){0.f,0.f,0.f,0.f};
  float lsum[2] = {0.f, 0.f};

#define ATTN_BODY(KT, K0,K1,K2,K3, V0,V1,V2,V3, L0,L1,L2,L3, M0,M1,M2,M3)       \
  {                                                                             \
    barrier_lgkm();  /* all waves done reading Ks/Vs of prev tile */            \
    *(uint4*)&Ks[krow     ][kcol] = K0;                                         \
    *(uint4*)&Ks[krow + 32][kcol] = K1;                                         \
    *(uint4*)&Ks[krow + 64][kcol] = K2;                                         \
    *(uint4*)&Ks[krow + 96][kcol] = K3;                                         \
    *(uint4*)&Vs[vrow     ][vcol] = V0;                                         \
    *(uint4*)&Vs[vrow + 16][vcol] = V1;                                         \
    *(uint4*)&Vs[vrow + 32][vcol] = V2;                                         \
    *(uint4*)&Vs[vrow + 48][vcol] = V3;                                         \
    if ((KT) < 15){                                                             \
      const bf16* kp2 = kbase + (size_t)(((KT)+1)*128)*EMBED + kcol;            \
      const bf16* vp2 = vbase + ((KT)+1)*128 + vcol;                            \
      L0 = *(const uint4*)(kp2 + (size_t)(krow     )*EMBED);                    \
      L1 = *(const uint4*)(kp2 + (size_t)(krow + 32)*EMBED);                    \
      L2 = *(const uint4*)(kp2 + (size_t)(krow + 64)*EMBED);                    \
      L3 = *(const uint4*)(kp2 + (size_t)(krow + 96)*EMBED);                    \
      M0 = *(const uint4*)(vp2 + (size_t)(vrow     )*SEQ);                      \
      M1 = *(const uint4*)(vp2 + (size_t)(vrow + 16)*SEQ);                      \
      M2 = *(const uint4*)(vp2 + (size_t)(vrow + 32)*SEQ);                      \
      M3 = *(const uint4*)(vp2 + (size_t)(vrow + 48)*SEQ);                      \
    }                                                                           \
    barrier_lgkm();  /* Ks/Vs ready; prefetch loads keep flying */              \
    float wvv[2][4][4];                                                         \
    _Pragma("unroll")                                                           \
    for (int mt = 0; mt < 2; ++mt){                                             \
      const float* lcol = &lutT[0][qh*32 + mt*16 + l15];                        \
      _Pragma("unroll")                                                         \
      for (int nt = 0; nt < 4; ++nt){                                           \
        int32x4 v = nid[mt][nt];                                                \
        wvv[mt][nt][0] = lcol[v[0] * 65];                                       \
        wvv[mt][nt][1] = lcol[v[1] * 65];                                       \
        wvv[mt][nt][2] = lcol[v[2] * 65];                                       \
        wvv[mt][nt][3] = lcol[v[3] * 65];                                       \
      }                                                                         \
    }                                                                           \
    if ((KT) < 15){                                                             \
      _Pragma("unroll")                                                         \
      for (int mt = 0; mt < 2; ++mt)                                            \
        _Pragma("unroll")                                                       \
        for (int nt = 0; nt < 4; ++nt)                                          \
          nid[mt][nt] = *(const int32x4*)(ids + idb                             \
              + (size_t)(q0 + qh*32 + mt*16 + l15)*SEQ                          \
              + (((KT)+1)*128) + kh*64 + nt*16 + quad*4);                       \
    }                                                                           \
    f32x4 sf[2][4];                                                             \
    __builtin_amdgcn_s_setprio(1);                                              \
    _Pragma("unroll")                                                           \
    for (int nt = 0; nt < 4; ++nt){                                             \
      bf16x8 ak0 = *(const bf16x8*)&Ks[kh*64 + nt*16 + l15][quad*8];            \
      bf16x8 ak1 = *(const bf16x8*)&Ks[kh*64 + nt*16 + l15][32 + quad*8];       \
      _Pragma("unroll")                                                         \
      for (int mt = 0; mt < 2; ++mt){                                           \
        f32x4 c = (f32x4){0.f,0.f,0.f,0.f};                                     \
        c = mfma16(ak0, bq[mt][0], c);                                          \
        c = mfma16(ak1, bq[mt][1], c);                                          \
        sf[mt][nt] = c;                                                         \
      }                                                                         \
    }                                                                           \
    __builtin_amdgcn_s_setprio(0);                                              \
    _Pragma("unroll")                                                           \
    for (int mt = 0; mt < 2; ++mt){                                             \
      _Pragma("unroll")                                                         \
      for (int nt = 0; nt < 4; ++nt){                                           \
        union { bf16 e[4]; uint2 u; } pk;                                       \
        float p0 = __builtin_amdgcn_exp2f(sf[mt][nt][0] + wvv[mt][nt][0]);      \
        float p1 = __builtin_amdgcn_exp2f(sf[mt][nt][1] + wvv[mt][nt][1]);      \
        float p2 = __builtin_amdgcn_exp2f(sf[mt][nt][2] + wvv[mt][nt][2]);      \
        float p3 = __builtin_amdgcn_exp2f(sf[mt][nt][3] + wvv[mt][nt][3]);      \
        pk.e[0] = (bf16)p0; pk.e[1] = (bf16)p1;                                 \
        pk.e[2] = (bf16)p2; pk.e[3] = (bf16)p3;                                 \
        lsum[mt] += (p0 + p1) + (p2 + p3);                                      \
        *(uint2*)&Ps[qh*32 + mt*16 + l15][kh*64 + nt*16 + quad*4] = pk.u;       \
      }                                                                         \
    }                                                                           \
    __builtin_amdgcn_s_setprio(1);                                              \
    _Pragma("unroll")                                                           \
    for (int ks = 0; ks < 2; ++ks){                                             \
      bf16x8 ap[2];                                                             \
      _Pragma("unroll")                                                         \
      for (int mt = 0; mt < 2; ++mt)                                            \
        ap[mt] = *(const bf16x8*)&Ps[qh*32 + mt*16 + l15][kh*64 + ks*32 + quad*8]; \
      _Pragma("unroll")                                                         \
      for (int nt = 0; nt < 4; ++nt){                                           \
        bf16x8 bv = *(const bf16x8*)&Vs[nt*16 + l15][kh*64 + ks*32 + quad*8];   \
        _Pragma("unroll")                                                       \
        for (int mt = 0; mt < 2; ++mt)                                          \
          acc[mt][nt] = mfma16(ap[mt], bv, acc[mt][nt]);                        \
      }                                                                         \
    }                                                                           \
    __builtin_amdgcn_s_setprio(0);                                              \
  }

  for (int kt2 = 0; kt2 < 16; kt2 += 2){
    ATTN_BODY(kt2,     ka0,ka1,ka2,ka3, va0,va1,va2,va3, kb0,kb1,kb2,kb3, vb0,vb1,vb2,vb3)
    ATTN_BODY(kt2 + 1, kb0,kb1,kb2,kb3, vb0,vb1,vb2,vb3, ka0,ka1,ka2,ka3, va0,va1,va2,va3)
  }
#undef ATTN_BODY

  // ---- epilogue (ALL acc indices compile-time; branches wave-uniform) ----
  __syncthreads();

  #pragma unroll
  for (int mt = 0; mt < 2; ++mt){
    float v = lsum[mt];
    v += __shfl_xor(v, 16);
    v += __shfl_xor(v, 32);
    if (quad == 0) lsum_s[kh*64 + qh*32 + mt*16 + l15] = v;
  }

  float* xch = (float*)&Ps[0][0];   // 2*32*65*4 = 16640 B <= 17408
  if (kh == 1){
    #pragma unroll
    for (int mt = 0; mt < 2; ++mt)
      #pragma unroll
      for (int nt = 0; nt < 4; ++nt){
        f32x4 a = acc[mt][nt];
        #pragma unroll
        for (int r = 0; r < 4; ++r)
          xch[(qh*32 + mt*16 + quad*4 + r)*65 + nt*16 + l15] = a[r];
      }
  }
  __syncthreads();

  if (kh == 0){
    #pragma unroll
    for (int mt = 0; mt < 2; ++mt){
      #pragma unroll
      for (int r = 0; r < 4; ++r){
        int ql = qh*32 + mt*16 + quad*4 + r;
        float inv = __builtin_amdgcn_rcpf(lsum_s[ql] + lsum_s[64 + ql]);
        #pragma unroll
        for (int nt = 0; nt < 4; ++nt){
          float o = acc[mt][nt][r] + xch[ql*65 + nt*16 + l15];
          Out[(size_t)(b*SEQ + q0 + ql)*EMBED + h*HD + nt*16 + l15] = (bf16)(o*inv);
        }
      }
    }
  }
}

// ---------------- launch ----------------
extern "C" void kernel_launch(void* const* d_in, const int* in_sizes, int n_in,
                              void* d_out, int out_size, void* d_ws, size_t ws_size,
                              hipStream_t stream)
{
  (void)in_sizes; (void)n_in; (void)out_size;
  const float* Q  = (const float*)d_in[0];
  const float* K  = (const float*)d_in[1];
  const float* V  = (const float*)d_in[2];
  const int*   ID = (const int*)d_in[3];
  const float* Wq = (const float*)d_in[4];
  const float* Wk = (const float*)d_in[5];
  const float* Wv = (const float*)d_in[6];
  const float* Wo = (const float*)d_in[7];
  const float* RE = (const float*)d_in[8];
  float* out = (float*)d_out;

  const size_t MB = (size_t)1 << 20;
  if (ws_size < 36*MB) return;
  char* ws = (char*)d_ws;
  bf16*  Qb    = (bf16*)(ws + 0*MB);             // dead after proj -> AO overlay
  bf16*  Kb    = (bf16*)(ws + 4*MB);
  bf16*  Vb    = (bf16*)(ws + 8*MB);
  bf16*  Qp    = (bf16*)(ws + 12*MB);
  bf16*  Kp    = (bf16*)(ws + 16*MB);
  bf16*  Vt    = (bf16*)(ws + 20*MB);            // (b,h,d,s) written by proj z==2
  bf16*  Wall  = (bf16*)(ws + 24*MB);            // 2 MB (Wq',Wk',Wv',Wo')
  bf16*  Wop   = Wall + (size_t)3*262144;
  bf16*  Rb    = (bf16*)(ws + 26*MB);            // 48 KB
  bf16*  AO    = (bf16*)(ws + 0*MB);             // overlays Qb

  k_prep      <<<dim3(8032),    256, 0, stream>>>(Q, K, V, Wq, Wk, Wv, Wo, RE,
                                                  Qb, Kb, Vb, Wall, Rb);
  k_proj      <<<dim3(4,32,3),  256, 0, stream>>>(Qb, Kb, Vb, Wall, Qp, Kp, Vt);
  k_attn      <<<dim3(32,8,2),  256, 0, stream>>>(Qp, Kp, Vt, Rb, ID, AO);
  k_gemm_out  <<<dim3(4,32),    256, 0, stream>>>(AO, Wop, out);
}